// Round 14
// baseline (153.369 us; speedup 1.0000x reference)
//
#include <hip/hip_runtime.h>
#include <hip/hip_fp16.h>
#include <math.h>

// Caps1D dynamic routing — fp16 W records, dot2 build+sweep, LDS u_ji,
// chunk-4 double-buffered build PINNED with sched_barrier.
//
// u: [B=1024, R=2336, M=4] fp32 ; W: [K=2, R=2336, M=4, P=16] fp32
// out[b,k] = norm/(1+norm) of final squashed routing sum.
//
// Measured history: r8 W-coalescing fix (162->112us), r10 pipelined build +
// distributed squash (->85), r11 dot2 sweep (->77), r13 dot2 build (83;
// fewer inst but shorter dep chains exposed more L2 latency at depth-1
// prefetch). r11's chunk-4 attempt was COLLAPSED by the scheduler (loads
// sunk to use; VGPR stayed 52). r14: pin the pipeline with
// __builtin_amdgcn_sched_barrier(0) between load-group and compute-group:
// 8 loads in flight per wave instead of 2.
// RULES (r12 failure): per-thread arrays fully-unrolled constant-indexed,
// unconditionally initialized, no whole-array type-punning.
// Constraints (r1-r9): 512 thr + launch_bounds(512,2) = 128 VGPR cap;
// 1024-thr blocks hard-capped at 64 VGPR (never again).

#define THREADS 512
#define NWAVE 8
#define RR 2336
#define KK 2

#if __has_builtin(__builtin_amdgcn_fdot2)
typedef _Float16 h2v __attribute__((ext_vector_type(2)));
static __device__ __forceinline__ float dot2h(__half2 a, __half2 b, float c) {
    h2v av, bv;
    __builtin_memcpy(&av, &a, 4);
    __builtin_memcpy(&bv, &b, 4);
    return __builtin_amdgcn_fdot2(av, bv, c, false);
}
#else
static __device__ __forceinline__ float dot2h(__half2 a, __half2 b, float c) {
    float2 fa = __half22float2(a), fb = __half22float2(b);
    return fmaf(fa.x, fb.x, fmaf(fa.y, fb.y, c));
}
#endif

#if __has_builtin(__builtin_amdgcn_sched_barrier)
#define SCHED_FENCE() __builtin_amdgcn_sched_barrier(0)
#else
#define SCHED_FENCE()
#endif

// ---- prepass: W fp32 [k][r][m][p] -> records {w01x,w23x,w01y,w23y} ----
// record j = (k*RR + r)*8 + p2, 4 half2 = 16 B:
//   w01x = (W[m0,2p2], W[m1,2p2])   w23x = (W[m2,2p2], W[m3,2p2])
//   w01y = (W[m0,2p2+1], W[m1,2p2+1])  w23y = (W[m2,2p2+1], W[m3,2p2+1])
__global__ __launch_bounds__(256)
void w_repack_kernel(const float* __restrict__ W, __half2* __restrict__ Wt)
{
    const int n = KK * RR * 8;                   // 37376 records
    for (int j = blockIdx.x * 256 + threadIdx.x; j < n; j += gridDim.x * 256) {
        const int p2 = j & 7;
        const int rk = j >> 3;                   // k*RR + r
        const float* wp = W + (size_t)rk * 64;   // [m][p], 64 floats
        const float x0 = wp[0*16 + 2*p2],     x1 = wp[1*16 + 2*p2];
        const float x2 = wp[2*16 + 2*p2],     x3 = wp[3*16 + 2*p2];
        const float y0 = wp[0*16 + 2*p2 + 1], y1 = wp[1*16 + 2*p2 + 1];
        const float y2 = wp[2*16 + 2*p2 + 1], y3 = wp[3*16 + 2*p2 + 1];
        __half2* o = Wt + (size_t)j * 4;
        o[0] = __floats2half2_rn(x0, x1);
        o[1] = __floats2half2_rn(x2, x3);
        o[2] = __floats2half2_rn(y0, y1);
        o[3] = __floats2half2_rn(y2, y3);
    }
}

// load 4 build steps (chunk c; rows c*256 + q*64 + rbase, all < 2304)
#define LOAD_CHUNK(c, uu, wv)                                          \
    {                                                                  \
        _Pragma("unroll")                                              \
        for (int q = 0; q < 4; ++q) {                                  \
            const int r = (c) * 256 + q * 64 + rbase;                  \
            uu[q] = u4p[b * RR + r];                                   \
            wv[q] = w4t[(size_t)r * 8];                                \
        }                                                              \
    }

// compute 4 build steps from buffered registers (guard-free)
#define COMP_CHUNK(c, uu, wv)                                          \
    {                                                                  \
        _Pragma("unroll")                                              \
        for (int q = 0; q < 4; ++q) {                                  \
            const int r = (c) * 256 + q * 64 + rbase;                  \
            const __half2 u01 = __floats2half2_rn(uu[q].x, uu[q].y);   \
            const __half2 u23 = __floats2half2_rn(uu[q].z, uu[q].w);   \
            const __half2* hm = (const __half2*)&wv[q];                \
            const float ax = dot2h(u01, hm[0], dot2h(u23, hm[1], 0.0f)); \
            const float ay = dot2h(u01, hm[2], dot2h(u23, hm[3], 0.0f)); \
            sA += ax; sB += ay;                                        \
            *(__half2*)(uji + r * 16 + p2 * 2) =                       \
                __floats2half2_rn(ax, ay);                             \
        }                                                              \
    }

__global__ __launch_bounds__(THREADS, 2)
void caps_routing_kernel(const float* __restrict__ u,
                         const __half2* __restrict__ Wt,
                         float* __restrict__ out)
{
    __shared__ __half uji[RR * 16];              // 74752 B
    __shared__ float  red[2][NWAVE][17];         // double-buffered partials

    const int bi   = blockIdx.x;                 // 2048 blocks
    const int b    = bi >> 1;
    const int k    = bi & 1;
    const int tid  = threadIdx.x;
    const int lane = tid & 63;
    const int wave = tid >> 6;
    const int p2   = lane & 7;                   // half2 column pair 0..7
    const int g    = lane >> 3;                  // row-in-group 0..7

    const float4* __restrict__ u4p = (const float4*)u;
    const float4* __restrict__ w4t = (const float4*)Wt + (size_t)k * RR * 8 + p2;

    // ---- build u_ji (fp16 -> LDS) + iter-0 sums; chunk-4 pipeline ----
    // 9 chunks x 4 steps = rows 0..2303 guard-free; tail = rows 2304..2335
    // (exactly waves 0..3, wave-uniform branch).
    float sA = 0.0f, sB = 0.0f;
    {
        const int rbase = wave * 8 + g;
        float4 uuA[4], wvA[4], uuB[4], wvB[4];
        LOAD_CHUNK(0, uuA, wvA)
        SCHED_FENCE();
        #pragma unroll
        for (int c = 0; c < 8; c += 2) {
            LOAD_CHUNK(c + 1, uuB, wvB)
            SCHED_FENCE();
            COMP_CHUNK(c, uuA, wvA)
            LOAD_CHUNK(c + 2, uuA, wvA)
            SCHED_FENCE();
            COMP_CHUNK(c + 1, uuB, wvB)
        }
        COMP_CHUNK(8, uuA, wvA)
        if (wave < 4) {                          // tail rows 2304..2335
            const int r = 2304 + rbase;
            const float4 uu = u4p[b * RR + r];
            const float4 wv = w4t[(size_t)r * 8];
            const __half2 u01 = __floats2half2_rn(uu.x, uu.y);
            const __half2 u23 = __floats2half2_rn(uu.z, uu.w);
            const __half2* hm = (const __half2*)&wv;
            const float ax = dot2h(u01, hm[0], dot2h(u23, hm[1], 0.0f));
            const float ay = dot2h(u01, hm[2], dot2h(u23, hm[3], 0.0f));
            sA += ax; sB += ay;
            *(__half2*)(uji + r * 16 + p2 * 2) = __floats2half2_rn(ax, ay);
        }
    }
    // iter-0 partials: reduce over g (xor 8/16/32 preserves p2)
    sA += __shfl_xor(sA, 8);  sB += __shfl_xor(sB, 8);
    sA += __shfl_xor(sA, 16); sB += __shfl_xor(sB, 16);
    sA += __shfl_xor(sA, 32); sB += __shfl_xor(sB, 32);
    if (lane < 8) {
        red[0][wave][2 * p2]     = sA;
        red[0][wave][2 * p2 + 1] = sB;
    }
    __syncthreads();                             // barrier 1: uji + red[0] ready

    float vcum[8];                               // this lane's v[(lane&1)*8+i]

    // ---- distributed squash, iter 0 (se == RR exactly) ----
    {
        float col = 0.0f;
        if (lane < 16) {
            #pragma unroll
            for (int w = 0; w < NWAVE; ++w) col += red[0][w][lane];
        }
        float nr = col * col;
        nr += __shfl_xor(nr, 1);
        nr += __shfl_xor(nr, 2);
        nr += __shfl_xor(nr, 4);
        nr += __shfl_xor(nr, 8);
        const float inv  = 1.0f / (float)RR;
        const float norm = nr * inv * inv;
        const float f    = sqrtf(norm) / (1.0f + norm);
        const float vnew = col * inv * f;        // valid in lanes 0..15
        #pragma unroll
        for (int i = 0; i < 8; ++i) vcum[i] = __shfl(vnew, (lane & 1) * 8 + i);
    }

    // ---- iterations 1,2: sweep + distributed squash (r11 form, verbatim) ----
    #pragma unroll 1
    for (int it = 1; it < 3; ++it) {
        const int buf = it & 1;

        __half2 v2[4];
        #pragma unroll
        for (int i = 0; i < 4; ++i) v2[i] = __floats2half2_rn(vcum[2*i], vcum[2*i+1]);

        // issue all 10 row-loads up front, clamped + unconditional
        float4 raw[10];
        #pragma unroll
        for (int s = 0; s < 10; ++s) {
            int row = s * 256 + wave * 32 + (lane >> 1);
            row = (row < RR) ? row : (RR - 1);
            raw[s] = *(const float4*)((const char*)uji + row * 32 + (lane & 1) * 16);
        }

        float s8[8] = {0,0,0,0,0,0,0,0};
        float se = 0.0f;
        #pragma unroll
        for (int s = 0; s < 10; ++s) {
            const bool ok = (s * 256 + wave * 32 + (lane >> 1)) < RR;
            const __half2* hp = (const __half2*)&raw[s];
            float d = dot2h(hp[0], v2[0],
                      dot2h(hp[1], v2[1],
                      dot2h(hp[2], v2[2],
                      dot2h(hp[3], v2[3], 0.0f))));
            d += __shfl_xor(d, 1);               // join the two half-dots
            float e = ok ? __expf(d) : 0.0f;     // no max-subtract (bounded)
            se += e;
            #pragma unroll
            for (int q = 0; q < 4; ++q) {
                float2 f = __half22float2(hp[q]);
                s8[2*q]   = fmaf(f.x, e, s8[2*q]);
                s8[2*q+1] = fmaf(f.y, e, s8[2*q+1]);
            }
        }

        // parity-preserving xor reduction (offsets 2..32 keep lane bit0)
        #pragma unroll
        for (int o = 2; o <= 32; o <<= 1) {
            se += __shfl_xor(se, o);
            #pragma unroll
            for (int i = 0; i < 8; ++i) s8[i] += __shfl_xor(s8[i], o);
        }
        if (lane < 2) {
            #pragma unroll
            for (int i = 0; i < 8; ++i) red[buf][wave][(lane & 1) * 8 + i] = s8[i];
            if (lane == 0) red[buf][wave][16] = se;
        }
        __syncthreads();                         // barrier 2 / 3

        // distributed squash from red[buf]
        {
            float col = 0.0f;
            if (lane < 17) {
                #pragma unroll
                for (int w = 0; w < NWAVE; ++w) col += red[buf][w][lane];
            }
            float nr = col * col;
            nr += __shfl_xor(nr, 1);
            nr += __shfl_xor(nr, 2);
            nr += __shfl_xor(nr, 4);
            nr += __shfl_xor(nr, 8);
            const float se_t = __shfl(col, 16);  // lane 16 carried sum(e)
            const float inv  = 1.0f / se_t;
            const float norm = nr * inv * inv;
            if (it == 1) {
                const float f    = sqrtf(norm) / (1.0f + norm);
                const float vnew = col * inv * f;
                #pragma unroll
                for (int i = 0; i < 8; ++i) vcum[i] += __shfl(vnew, (lane & 1) * 8 + i);
            } else if (wave == 0 && lane == 0) {
                out[b * KK + k] = norm / (1.0f + norm);
            }
        }
    }
}

extern "C" void kernel_launch(void* const* d_in, const int* in_sizes, int n_in,
                              void* d_out, int out_size, void* d_ws, size_t ws_size,
                              hipStream_t stream) {
    const float* u = (const float*)d_in[0];   // [1024, 2336, 4]
    const float* W = (const float*)d_in[1];   // [2, 2336, 4, 16]
    float* out = (float*)d_out;               // [1024, 2]
    __half2* Wt = (__half2*)d_ws;             // 299008 B of scratch

    w_repack_kernel<<<dim3(256), dim3(256), 0, stream>>>(W, Wt);
    caps_routing_kernel<<<dim3(2048), dim3(THREADS), 0, stream>>>(u, Wt, out);
}

// Round 15
// 129.038 us; speedup vs baseline: 1.1886x; 1.1886x over previous
//
#include <hip/hip_runtime.h>
#include <hip/hip_fp16.h>
#include <math.h>

// Caps1D dynamic routing — fp16 W records, dot2 build+sweep, LDS u_ji,
// TWO-STREAM named-register prefetch build (4 loads in flight, no fences).
//
// u: [B=1024, R=2336, M=4] fp32 ; W: [K=2, R=2336, M=4, P=16] fp32
// out[b,k] = norm/(1+norm) of final squashed routing sum.
//
// Measured history: r8 W-coalescing fix (162->112us steady), r10 depth-1
// named-var prefetch + distributed squash (->85), r11 dot2 sweep (->77),
// r13 dot2 build (83: fewer inst, more exposed latency), r14 sched_barrier
// pipeline (105: hard fences kill wave-switching — occupancy 40->21%).
// Only the NAMED-VARIABLE depth-1 prefetch ever survived compilation
// (array chunks get sunk [r11] or scratch-homed [r12]). r15 doubles it:
// two independent row streams, each with its own scalar prefetch regs ->
// 4 outstanding loads/wave, zero fences.
// RULES (r12): per-thread arrays fully-unrolled constant-indexed,
// unconditionally initialized, no whole-array type-punning.
// Constraints (r1-r9): 512 thr + launch_bounds(512,2) = 128 VGPR cap;
// 1024-thr blocks hard-capped at 64 VGPR.

#define THREADS 512
#define NWAVE 8
#define RR 2336
#define KK 2

#if __has_builtin(__builtin_amdgcn_fdot2)
typedef _Float16 h2v __attribute__((ext_vector_type(2)));
static __device__ __forceinline__ float dot2h(__half2 a, __half2 b, float c) {
    h2v av, bv;
    __builtin_memcpy(&av, &a, 4);
    __builtin_memcpy(&bv, &b, 4);
    return __builtin_amdgcn_fdot2(av, bv, c, false);
}
#else
static __device__ __forceinline__ float dot2h(__half2 a, __half2 b, float c) {
    float2 fa = __half22float2(a), fb = __half22float2(b);
    return fmaf(fa.x, fb.x, fmaf(fa.y, fb.y, c));
}
#endif

// ---- prepass: W fp32 [k][r][m][p] -> records {w01x,w23x,w01y,w23y} ----
// record j = (k*RR + r)*8 + p2, 4 half2 = 16 B:
//   w01x = (W[m0,2p2], W[m1,2p2])   w23x = (W[m2,2p2], W[m3,2p2])
//   w01y = (W[m0,2p2+1], W[m1,2p2+1])  w23y = (W[m2,2p2+1], W[m3,2p2+1])
__global__ __launch_bounds__(256)
void w_repack_kernel(const float* __restrict__ W, __half2* __restrict__ Wt)
{
    const int n = KK * RR * 8;                   // 37376 records
    for (int j = blockIdx.x * 256 + threadIdx.x; j < n; j += gridDim.x * 256) {
        const int p2 = j & 7;
        const int rk = j >> 3;                   // k*RR + r
        const float* wp = W + (size_t)rk * 64;   // [m][p], 64 floats
        const float x0 = wp[0*16 + 2*p2],     x1 = wp[1*16 + 2*p2];
        const float x2 = wp[2*16 + 2*p2],     x3 = wp[3*16 + 2*p2];
        const float y0 = wp[0*16 + 2*p2 + 1], y1 = wp[1*16 + 2*p2 + 1];
        const float y2 = wp[2*16 + 2*p2 + 1], y3 = wp[3*16 + 2*p2 + 1];
        __half2* o = Wt + (size_t)j * 4;
        o[0] = __floats2half2_rn(x0, x1);
        o[1] = __floats2half2_rn(x2, x3);
        o[2] = __floats2half2_rn(y0, y1);
        o[3] = __floats2half2_rn(y2, y3);
    }
}

__global__ __launch_bounds__(THREADS, 2)
void caps_routing_kernel(const float* __restrict__ u,
                         const __half2* __restrict__ Wt,
                         float* __restrict__ out)
{
    __shared__ __half uji[RR * 16];              // 74752 B
    __shared__ float  red[2][NWAVE][17];         // double-buffered partials

    const int bi   = blockIdx.x;                 // 2048 blocks
    const int b    = bi >> 1;
    const int k    = bi & 1;
    const int tid  = threadIdx.x;
    const int lane = tid & 63;
    const int wave = tid >> 6;
    const int p2   = lane & 7;                   // half2 column pair 0..7
    const int g    = lane >> 3;                  // row-in-group 0..7

    const float4* __restrict__ u4p = (const float4*)u;
    const float4* __restrict__ w4t = (const float4*)Wt + (size_t)k * RR * 8 + p2;

    // ---- build u_ji (fp16 -> LDS) + iter-0 sums; two-stream prefetch ----
    // stream A rows [0,1152), stream B rows [1152,2304): 18 steps each,
    // all guard-free; tail rows 2304..2335 = waves 0..3 (wave-uniform).
    float sA = 0.0f, sB = 0.0f;
    {
        const int rbase = wave * 8 + g;
        float4 uuA_n = u4p[b * RR + rbase];
        float4 wvA_n = w4t[(size_t)rbase * 8];
        float4 uuB_n = u4p[b * RR + 1152 + rbase];
        float4 wvB_n = w4t[(size_t)(1152 + rbase) * 8];
        #pragma unroll 3
        for (int i = 0; i < 18; ++i) {
            const float4 uuA = uuA_n, wvA = wvA_n;
            const float4 uuB = uuB_n, wvB = wvB_n;
            if (i + 1 < 18) {                    // prefetch both streams
                const int ra = (i + 1) * 64 + rbase;
                uuA_n = u4p[b * RR + ra];
                wvA_n = w4t[(size_t)ra * 8];
                const int rb = 1152 + (i + 1) * 64 + rbase;
                uuB_n = u4p[b * RR + rb];
                wvB_n = w4t[(size_t)rb * 8];
            }
            {   // stream A compute
                const int r = i * 64 + rbase;
                const __half2 u01 = __floats2half2_rn(uuA.x, uuA.y);
                const __half2 u23 = __floats2half2_rn(uuA.z, uuA.w);
                const __half2* hm = (const __half2*)&wvA;
                const float ax = dot2h(u01, hm[0], dot2h(u23, hm[1], 0.0f));
                const float ay = dot2h(u01, hm[2], dot2h(u23, hm[3], 0.0f));
                sA += ax; sB += ay;
                *(__half2*)(uji + r * 16 + p2 * 2) = __floats2half2_rn(ax, ay);
            }
            {   // stream B compute
                const int r = 1152 + i * 64 + rbase;
                const __half2 u01 = __floats2half2_rn(uuB.x, uuB.y);
                const __half2 u23 = __floats2half2_rn(uuB.z, uuB.w);
                const __half2* hm = (const __half2*)&wvB;
                const float ax = dot2h(u01, hm[0], dot2h(u23, hm[1], 0.0f));
                const float ay = dot2h(u01, hm[2], dot2h(u23, hm[3], 0.0f));
                sA += ax; sB += ay;
                *(__half2*)(uji + r * 16 + p2 * 2) = __floats2half2_rn(ax, ay);
            }
        }
        if (wave < 4) {                          // tail rows 2304..2335
            const int r = 2304 + rbase;
            const float4 uu = u4p[b * RR + r];
            const float4 wv = w4t[(size_t)r * 8];
            const __half2 u01 = __floats2half2_rn(uu.x, uu.y);
            const __half2 u23 = __floats2half2_rn(uu.z, uu.w);
            const __half2* hm = (const __half2*)&wv;
            const float ax = dot2h(u01, hm[0], dot2h(u23, hm[1], 0.0f));
            const float ay = dot2h(u01, hm[2], dot2h(u23, hm[3], 0.0f));
            sA += ax; sB += ay;
            *(__half2*)(uji + r * 16 + p2 * 2) = __floats2half2_rn(ax, ay);
        }
    }
    // iter-0 partials: reduce over g (xor 8/16/32 preserves p2)
    sA += __shfl_xor(sA, 8);  sB += __shfl_xor(sB, 8);
    sA += __shfl_xor(sA, 16); sB += __shfl_xor(sB, 16);
    sA += __shfl_xor(sA, 32); sB += __shfl_xor(sB, 32);
    if (lane < 8) {
        red[0][wave][2 * p2]     = sA;
        red[0][wave][2 * p2 + 1] = sB;
    }
    __syncthreads();                             // barrier 1: uji + red[0] ready

    float vcum[8];                               // this lane's v[(lane&1)*8+i]

    // ---- distributed squash, iter 0 (se == RR exactly) ----
    {
        float col = 0.0f;
        if (lane < 16) {
            #pragma unroll
            for (int w = 0; w < NWAVE; ++w) col += red[0][w][lane];
        }
        float nr = col * col;
        nr += __shfl_xor(nr, 1);
        nr += __shfl_xor(nr, 2);
        nr += __shfl_xor(nr, 4);
        nr += __shfl_xor(nr, 8);
        const float inv  = 1.0f / (float)RR;
        const float norm = nr * inv * inv;
        const float f    = sqrtf(norm) / (1.0f + norm);
        const float vnew = col * inv * f;        // valid in lanes 0..15
        #pragma unroll
        for (int i = 0; i < 8; ++i) vcum[i] = __shfl(vnew, (lane & 1) * 8 + i);
    }

    // ---- iterations 1,2: sweep + distributed squash (r11/r13 form) ----
    #pragma unroll 1
    for (int it = 1; it < 3; ++it) {
        const int buf = it & 1;

        __half2 v2[4];
        #pragma unroll
        for (int i = 0; i < 4; ++i) v2[i] = __floats2half2_rn(vcum[2*i], vcum[2*i+1]);

        // issue all 10 row-loads up front, clamped + unconditional
        float4 raw[10];
        #pragma unroll
        for (int s = 0; s < 10; ++s) {
            int row = s * 256 + wave * 32 + (lane >> 1);
            row = (row < RR) ? row : (RR - 1);
            raw[s] = *(const float4*)((const char*)uji + row * 32 + (lane & 1) * 16);
        }

        float s8[8] = {0,0,0,0,0,0,0,0};
        float se = 0.0f;
        #pragma unroll
        for (int s = 0; s < 10; ++s) {
            const bool ok = (s * 256 + wave * 32 + (lane >> 1)) < RR;
            const __half2* hp = (const __half2*)&raw[s];
            float d = dot2h(hp[0], v2[0],
                      dot2h(hp[1], v2[1],
                      dot2h(hp[2], v2[2],
                      dot2h(hp[3], v2[3], 0.0f))));
            d += __shfl_xor(d, 1);               // join the two half-dots
            float e = ok ? __expf(d) : 0.0f;     // no max-subtract (bounded)
            se += e;
            #pragma unroll
            for (int q = 0; q < 4; ++q) {
                float2 f = __half22float2(hp[q]);
                s8[2*q]   = fmaf(f.x, e, s8[2*q]);
                s8[2*q+1] = fmaf(f.y, e, s8[2*q+1]);
            }
        }

        // parity-preserving xor reduction (offsets 2..32 keep lane bit0)
        #pragma unroll
        for (int o = 2; o <= 32; o <<= 1) {
            se += __shfl_xor(se, o);
            #pragma unroll
            for (int i = 0; i < 8; ++i) s8[i] += __shfl_xor(s8[i], o);
        }
        if (lane < 2) {
            #pragma unroll
            for (int i = 0; i < 8; ++i) red[buf][wave][(lane & 1) * 8 + i] = s8[i];
            if (lane == 0) red[buf][wave][16] = se;
        }
        __syncthreads();                         // barrier 2 / 3

        // distributed squash from red[buf]
        {
            float col = 0.0f;
            if (lane < 17) {
                #pragma unroll
                for (int w = 0; w < NWAVE; ++w) col += red[buf][w][lane];
            }
            float nr = col * col;
            nr += __shfl_xor(nr, 1);
            nr += __shfl_xor(nr, 2);
            nr += __shfl_xor(nr, 4);
            nr += __shfl_xor(nr, 8);
            const float se_t = __shfl(col, 16);  // lane 16 carried sum(e)
            const float inv  = 1.0f / se_t;
            const float norm = nr * inv * inv;
            if (it == 1) {
                const float f    = sqrtf(norm) / (1.0f + norm);
                const float vnew = col * inv * f;
                #pragma unroll
                for (int i = 0; i < 8; ++i) vcum[i] += __shfl(vnew, (lane & 1) * 8 + i);
            } else if (wave == 0 && lane == 0) {
                out[b * KK + k] = norm / (1.0f + norm);
            }
        }
    }
}

extern "C" void kernel_launch(void* const* d_in, const int* in_sizes, int n_in,
                              void* d_out, int out_size, void* d_ws, size_t ws_size,
                              hipStream_t stream) {
    const float* u = (const float*)d_in[0];   // [1024, 2336, 4]
    const float* W = (const float*)d_in[1];   // [2, 2336, 4, 16]
    float* out = (float*)d_out;               // [1024, 2]
    __half2* Wt = (__half2*)d_ws;             // 299008 B of scratch

    w_repack_kernel<<<dim3(256), dim3(256), 0, stream>>>(W, Wt);
    caps_routing_kernel<<<dim3(2048), dim3(THREADS), 0, stream>>>(u, Wt, out);
}